// Round 7
// baseline (353.677 us; speedup 1.0000x reference)
//
#include <hip/hip_runtime.h>
#include <hip/hip_bf16.h>

typedef __attribute__((ext_vector_type(8))) short short8;
typedef __attribute__((ext_vector_type(4))) short short4v;
typedef __attribute__((ext_vector_type(4))) float f32x4;
typedef __hip_bfloat16 bf16;

#define SEQ 2048
#define DIM 2048
#define NH 32
#define NKV 8
#define HD 64
#define QKVD 3072
#define KVD 512
#define SMSCALE 0.18033688011112042f  /* 0.125 * log2(e), folded into Q in gemm1 epilogue */

__device__ inline void gld_lds16(const bf16* g, bf16* l) {
    __builtin_amdgcn_global_load_lds((const __attribute__((address_space(1))) void*)g,
                                     (__attribute__((address_space(3))) void*)l, 16, 0, 0);
}

__device__ inline unsigned pkbf16(float a, float b) {
    __hip_bfloat162 h = __float22bfloat162_rn(make_float2(a, b));
    return *(unsigned*)&h;
}

union PB { short4v s; unsigned u[2]; };

// ---------------- fused fp32 -> bf16 convert for x | wqkv | wo ----------------
__global__ void cvt3_kernel(const float* __restrict__ x, const float* __restrict__ wqkv,
                            const float* __restrict__ wo, bf16* __restrict__ out) {
    int i = blockIdx.x * blockDim.x + threadIdx.x;
    const float* src; int off;
    if (i < 2097152) { src = x; off = i; }
    else if (i < 3670016) { src = wqkv; off = i - 2097152; }
    else { src = wo; off = i - 3670016; }
    float4 v = ((const float4*)src)[off];
    uint2 u;
    u.x = pkbf16(v.x, v.y);
    u.y = pkbf16(v.z, v.w);
    ((uint2*)out)[i] = u;
}

// ---------------- NT GEMM (m97 structure) with fused epilogues ----------------
// EPI=1: plain fp32 store to C.  EPI=2: rope+split epilogue -> qr (scaled), kr, vt (transposed).
template <int EPI>
__global__ __launch_bounds__(256, 3) void gemm_nt(const bf16* __restrict__ A,
                                                  const bf16* __restrict__ Bt,
                                                  float* __restrict__ C,
                                                  const float* __restrict__ fc,
                                                  bf16* __restrict__ qr,
                                                  bf16* __restrict__ kr,
                                                  bf16* __restrict__ vt,
                                                  int M, int N, int K) {
    __shared__ bf16 As[128 * 32];
    __shared__ bf16 Bs[128 * 32];
    const int tid = threadIdx.x;
    const int lane = tid & 63;
    const int quad = lane >> 4;
    const int r16 = lane & 15;
    const int wave = tid >> 6;
    const int bm = blockIdx.y * 128;
    const int bn = blockIdx.x * 128;
    const int wm = (wave >> 1) * 64;
    const int wn = (wave & 1) * 64;

    f32x4 acc[4][4] = {};

    const int arow = tid >> 2;
    const int kch = (tid & 3) * 8;
    const bf16* Ap = A + (size_t)(bm + arow) * K + kch;
    const bf16* Bp = Bt + (size_t)(bn + arow) * K + kch;
    bf16* Asd = As + tid * 8;
    bf16* Bsd = Bs + tid * 8;
    const int kq = quad * 8;

    for (int k0 = 0; k0 < K; k0 += 32) {
        __syncthreads();
        gld_lds16(Ap, Asd);
        gld_lds16(Ap + (size_t)64 * K, Asd + 64 * 32);
        gld_lds16(Bp, Bsd);
        gld_lds16(Bp + (size_t)64 * K, Bsd + 64 * 32);
        Ap += 32; Bp += 32;
        __syncthreads();
        short8 af[4], bfr[4];
#pragma unroll
        for (int i = 0; i < 4; i++)
            af[i] = *(const short8*)(As + (wm + i * 16 + r16) * 32 + kq);
#pragma unroll
        for (int j = 0; j < 4; j++)
            bfr[j] = *(const short8*)(Bs + (wn + j * 16 + r16) * 32 + kq);
#pragma unroll
        for (int i = 0; i < 4; i++)
#pragma unroll
            for (int j = 0; j < 4; j++)
                acc[i][j] = __builtin_amdgcn_mfma_f32_16x16x32_bf16(af[i], bfr[j], acc[i][j], 0, 0, 0);
    }

    if (EPI == 1) {
#pragma unroll
        for (int i = 0; i < 4; i++)
#pragma unroll
            for (int j = 0; j < 4; j++) {
                int row = bm + wm + i * 16 + quad * 4;
                int col = bn + wn + j * 16 + r16;
#pragma unroll
                for (int r = 0; r < 4; r++)
                    C[(size_t)(row + r) * N + col] = acc[i][j][r];
            }
    } else {
        // region is uniform per block (boundaries 2048/2560 are multiples of 128)
        const int odd = r16 & 1;
        if (bn < 2560) {
            // Q or K: rope. pairs (2c,2c+1) = adjacent lanes -> shfl_xor(1)
            const bool isQ = (bn < 2048);
            bf16* dst = isQ ? qr : kr;
            const int ld = isQ ? DIM : KVD;
            const int cofs = isQ ? 0 : 2048;
            const float scale = isQ ? SMSCALE : 1.0f;
#pragma unroll
            for (int i = 0; i < 4; i++)
#pragma unroll
                for (int j = 0; j < 4; j++) {
                    int col = bn + wn + j * 16 + r16;
                    int j2 = (col & 63) >> 1;
#pragma unroll
                    for (int r = 0; r < 4; r++) {
                        int row = bm + wm + i * 16 + quad * 4 + r;
                        int s = row & (SEQ - 1);
                        float v = acc[i][j][r];
                        float p = __shfl_xor(v, 1, 64);
                        float2 cs = *(const float2*)(fc + ((size_t)s * 32 + j2) * 2);
                        float ov = odd ? (v * cs.x + p * cs.y) : (v * cs.x - p * cs.y);
                        dst[(size_t)row * ld + (col - cofs)] = __float2bfloat16(ov * scale);
                    }
                }
        } else {
            // V: transpose into vt[(b*8+kvh)*64+d][2048]; 4 row-consecutive vals = 8B store
#pragma unroll
            for (int i = 0; i < 4; i++)
#pragma unroll
                for (int j = 0; j < 4; j++) {
                    int col = bn + wn + j * 16 + r16;
                    int cv = col - 2560;
                    int row0 = bm + wm + i * 16 + quad * 4;
                    int bb = row0 >> 11;
                    int s0 = row0 & (SEQ - 1);
                    bf16* dst = vt + (((size_t)(bb * NKV + (cv >> 6)) * HD + (cv & 63)) * SEQ + s0);
                    PB pk;
                    pk.u[0] = pkbf16(acc[i][j][0], acc[i][j][1]);
                    pk.u[1] = pkbf16(acc[i][j][2], acc[i][j][3]);
                    *(short4v*)dst = pk.s;
                }
        }
    }
}

// ---------------- Flash attention: cooperative, GQA-shared K/V, no-max softmax ----------------
// Block = (b, kvh, qt); 4 waves = 4 q-heads sharing K/V; 32-row q-tile per block.
// qt descending (longest blocks dispatch first). No running max (scores bounded; masked keys
// give exp2(-inf)=0). l computed by MFMA with A=ones (column sums), lane-uniform at epilogue.
// K/V double-buffered in LDS (chunk-major), staged via global_load_lds width-16.
__global__ __launch_bounds__(256, 3) void attn_kernel(const bf16* __restrict__ qr,
                                                      const bf16* __restrict__ kr,
                                                      const bf16* __restrict__ vt,
                                                      bf16* __restrict__ out) {
    __shared__ bf16 Ks[8192];  // [buf 2][dchunk 8][key 64][8]
    __shared__ bf16 Vs[8192];  // [buf 2][kchunk 8][d 64][8]
    const int t = threadIdx.x;
    const int lane = t & 63;
    const int wv = t >> 6;
    const int quad = lane >> 4;
    const int r16 = lane & 15;
    const int b = blockIdx.y >> 3;
    const int kvh = blockIdx.y & 7;
    const int qt = 63 - (int)blockIdx.x;
    const int q0 = qt * 32;
    const int nkb = (qt >> 1) + 1;
    const int h = kvh * 4 + wv;

    const bf16* Kg = kr + ((size_t)b * SEQ + (t & 63)) * KVD + kvh * HD + (t >> 6) * 8;
    const bf16* Vg = vt + ((size_t)(b * NKV + kvh) * HD + (t & 63)) * SEQ + (t >> 6) * 8;

    const char* kl = (const char*)Ks + quad * 1024 + r16 * 16;
    const char* vl = (const char*)Vs + (quad >> 1) * 1024 + r16 * 16 + (quad & 1) * 8;

    // Q fragments (B-operand of 16x16x32), pre-scaled by SMSCALE in gemm1 epilogue
    const bf16* Qp = qr + ((size_t)b * SEQ + q0 + r16) * DIM + h * HD + quad * 8;
    short8 qa[2][2];
#pragma unroll
    for (int qs = 0; qs < 2; qs++)
#pragma unroll
        for (int c = 0; c < 2; c++)
            qa[qs][c] = *(const short8*)(Qp + (size_t)qs * 16 * DIM + c * 32);

    f32x4 o[2][4] = {};
    f32x4 lacc[2] = {};
    const short ONE = (short)0x3F80;  // bf16 1.0
    const short4v onesA = {ONE, ONE, ONE, ONE};

    // prologue: stage tile 0 into buf 0
    {
        bf16* Ksd = Ks + t * 8;
        bf16* Vsd = Vs + t * 8;
        gld_lds16(Kg, Ksd);      gld_lds16(Kg + 32, Ksd + 2048);
        gld_lds16(Vg, Vsd);      gld_lds16(Vg + 32, Vsd + 2048);
    }

    for (int kb = 0; kb < nkb; kb++) {
        __syncthreads();
        const int buf = kb & 1;
        if (kb + 1 < nkb) {
            const bf16* Kgn = Kg + (size_t)(kb + 1) * 64 * KVD;
            const bf16* Vgn = Vg + (kb + 1) * 64;
            bf16* Ksd = Ks + (buf ^ 1) * 4096 + t * 8;
            bf16* Vsd = Vs + (buf ^ 1) * 4096 + t * 8;
            gld_lds16(Kgn, Ksd);      gld_lds16(Kgn + 32, Ksd + 2048);
            gld_lds16(Vgn, Vsd);      gld_lds16(Vgn + 32, Vsd + 2048);
        }
        const char* klb = kl + buf * 8192;
        const char* vlb = vl + buf * 8192;

        // S^T = K * Q^T (64 keys x 32 q-rows); K frags reused across 2 q-subtiles
        const f32x4 z = {0.f, 0.f, 0.f, 0.f};
        f32x4 st[4][2];
#pragma unroll
        for (int n = 0; n < 4; n++) {
            short8 kf0 = *(const short8*)(klb + n * 256);
            short8 kf1 = *(const short8*)(klb + 4096 + n * 256);
#pragma unroll
            for (int qs = 0; qs < 2; qs++) {
                st[n][qs] = __builtin_amdgcn_mfma_f32_16x16x32_bf16(kf0, qa[qs][0], z, 0, 0, 0);
                st[n][qs] = __builtin_amdgcn_mfma_f32_16x16x32_bf16(kf1, qa[qs][1], st[n][qs], 0, 0, 0);
            }
        }
        // V fragments issued early
        short4v vf[4][4];
#pragma unroll
        for (int dt = 0; dt < 4; dt++)
#pragma unroll
            for (int n = 0; n < 4; n++)
                vf[dt][n] = *(const short4v*)(vlb + n * 2048 + dt * 256);

        if (kb == nkb - 1) {  // only the diagonal staging block needs the causal mask
            const int kbase = kb * 64;
#pragma unroll
            for (int n = 0; n < 4; n++)
#pragma unroll
                for (int qs = 0; qs < 2; qs++)
#pragma unroll
                    for (int r = 0; r < 4; r++) {
                        int key = kbase + n * 16 + quad * 4 + r;
                        if (key > q0 + qs * 16 + r16) st[n][qs][r] = -__builtin_inff();
                    }
        }

        // p = exp2(s); l accumulated by MFMA (A=ones -> column sums), no VALU adds
        PB pbs[2][4];
#pragma unroll
        for (int qs = 0; qs < 2; qs++)
#pragma unroll
            for (int n = 0; n < 4; n++) {
                float p0 = exp2f(st[n][qs][0]);
                float p1 = exp2f(st[n][qs][1]);
                float p2 = exp2f(st[n][qs][2]);
                float p3 = exp2f(st[n][qs][3]);
                pbs[qs][n].u[0] = pkbf16(p0, p1);
                pbs[qs][n].u[1] = pkbf16(p2, p3);
            }
#pragma unroll
        for (int qs = 0; qs < 2; qs++)
#pragma unroll
            for (int n = 0; n < 4; n++)
                lacc[qs] = __builtin_amdgcn_mfma_f32_16x16x16bf16_1k(onesA, pbs[qs][n].s, lacc[qs], 0, 0, 0);

        // O^T += V^T * P^T
#pragma unroll
        for (int qs = 0; qs < 2; qs++)
#pragma unroll
            for (int dt = 0; dt < 4; dt++)
#pragma unroll
                for (int n = 0; n < 4; n++)
                    o[qs][dt] = __builtin_amdgcn_mfma_f32_16x16x16bf16_1k(vf[dt][n], pbs[qs][n].s, o[qs][dt], 0, 0, 0);
    }

    // epilogue: l is lane-uniform in lacc (all m-rows/quads equal); store O^T/l
#pragma unroll
    for (int qs = 0; qs < 2; qs++) {
        float inv_l = 1.f / lacc[qs][0];
        bf16* Op = out + ((size_t)b * SEQ + q0 + qs * 16 + r16) * DIM + h * HD + quad * 4;
#pragma unroll
        for (int dt = 0; dt < 4; dt++) {
            PB pk;
            pk.u[0] = pkbf16(o[qs][dt][0] * inv_l, o[qs][dt][1] * inv_l);
            pk.u[1] = pkbf16(o[qs][dt][2] * inv_l, o[qs][dt][3] * inv_l);
            *(short4v*)(Op + dt * 16) = pk.s;
        }
    }
}

extern "C" void kernel_launch(void* const* d_in, const int* in_sizes, int n_in,
                              void* d_out, int out_size, void* d_ws, size_t ws_size,
                              hipStream_t stream) {
    (void)in_sizes; (void)n_in; (void)out_size; (void)ws_size;
    const float* x    = (const float*)d_in[0];
    const float* fc   = (const float*)d_in[1];
    const float* wqkv = (const float*)d_in[3];
    const float* wo   = (const float*)d_in[4];
    float* out = (float*)d_out;

    char* w = (char*)d_ws;
    bf16* xb    = (bf16*)(w);              // 16 MB (A of gemm1; dead after -> attnb aliases)
    bf16* wqkvb = (bf16*)(w + 16777216);   // 12 MB
    bf16* wob   = (bf16*)(w + 29360128);   //  8 MB
    bf16* qr    = (bf16*)(w + 37748736);   // 16 MB
    bf16* kr    = (bf16*)(w + 54525952);   //  4 MB
    bf16* vt    = (bf16*)(w + 58720256);   //  4 MB -> total 60 MB
    bf16* attnb = xb;

    cvt3_kernel<<<18432, 256, 0, stream>>>(x, wqkv, wo, xb);
    gemm_nt<2><<<dim3(24, 32), 256, 0, stream>>>(xb, wqkvb, nullptr, fc, qr, kr, vt, 4096, QKVD, DIM);
    attn_kernel<<<dim3(64, 16), 256, 0, stream>>>(qr, kr, vt, attnb);
    gemm_nt<1><<<dim3(16, 32), 256, 0, stream>>>(attnb, wob, out, nullptr, nullptr, nullptr, nullptr, 4096, DIM, DIM);
}